// Round 10
// baseline (521.253 us; speedup 1.0000x reference)
//
#include <hip/hip_runtime.h>
#include <math.h>

#define NU   16384
#define NI   4096
#define DDIM 64
#define BB   2048
#define GSTR8 2056   // u8 g-tile stride: hi-group row offset = 2056*4 B -> 8 banks apart

typedef unsigned short u16;
typedef unsigned char  u8;
typedef __attribute__((ext_vector_type(8))) short short8;
typedef __attribute__((ext_vector_type(4))) float f32x4;

// fp32 -> bf16 RNE (embeddings feeding MFMA)
static __device__ __forceinline__ u16 f2bf(float f) {
    union { float f; unsigned int u; } v; v.f = f;
    unsigned int u = v.u + 0x7FFFu + ((v.u >> 16) & 1u);
    return (u16)(u >> 16);
}

// rating [1,5] -> u8 [1,201]; NaN -> 0 (v_cvt_u32_f32 clamps NaN to 0).
// decode gv = q*0.02 + 0.98, err <= 0.01
static __device__ __forceinline__ u8 enc_r(float r) {
    return (u8)__float2uint_rz(fmaf(r, 50.f, -48.5f));
}

// ===== k_qprep: Ubf[b][k]=bf16(E[uidx[b]][k]); qinfo[b]={ub, 1/|u|} =====
__global__ __launch_bounds__(256) void k_qprep(
    const float* __restrict__ E, const int* __restrict__ uidx,
    u16* __restrict__ Ubf, int2* __restrict__ qinfo)
{
    const int lane = threadIdx.x & 63;
    const int b = blockIdx.x * 4 + (threadIdx.x >> 6);
    const int ub = uidx[b];
    const float e = E[(size_t)ub * DDIM + lane];
    float ss = e * e;
#pragma unroll
    for (int o = 32; o > 0; o >>= 1) ss += __shfl_xor(ss, o);
    Ubf[b * DDIM + lane] = f2bf(e);
    if (lane == 0) qinfo[b] = make_int2(ub, __float_as_int(rsqrtf(ss)));
}

// ===== k_sums: guaranteed-BW-bound row sums/counts.
// One wave per quarter-row (4 KB): 4 independent coalesced float4 loads/lane,
// shfl reduce, 2 atomicAdds. No LDS. Block = 4 waves = exactly one row. =====
__global__ __launch_bounds__(256) void k_sums(
    const float* __restrict__ R, float* __restrict__ rowsum, float* __restrict__ rowcnt)
{
    const int lane = threadIdx.x & 63;
    const int row  = blockIdx.x;
    const int qtr  = threadIdx.x >> 6;
    const float4* R4 = (const float4*)(R + (size_t)row * NI) + qtr * 256;

    const float4 a = R4[lane];
    const float4 b = R4[lane + 64];
    const float4 c = R4[lane + 128];
    const float4 d = R4[lane + 192];

    float s = 0.f, cn = 0.f;
#define ACC(v) do { \
    if ((v).x == (v).x) { s += (v).x; cn += 1.f; } \
    if ((v).y == (v).y) { s += (v).y; cn += 1.f; } \
    if ((v).z == (v).z) { s += (v).z; cn += 1.f; } \
    if ((v).w == (v).w) { s += (v).w; cn += 1.f; } } while (0)
    ACC(a); ACC(b); ACC(c); ACC(d);
#undef ACC
#pragma unroll
    for (int o = 32; o > 0; o >>= 1) {
        s  += __shfl_xor(s, o);
        cn += __shfl_xor(cn, o);
    }
    if (lane == 0) {
        atomicAdd(&rowsum[row], s);
        atomicAdd(&rowcnt[row], cn);
    }
}

// ===== k_enorm: normInv[n] = 1/||E[n]||. One wave per row. =====
__global__ __launch_bounds__(256) void k_enorm(
    const float* __restrict__ E, float* __restrict__ normInv)
{
    const int lane = threadIdx.x & 63;
    const int n = blockIdx.x * 4 + (threadIdx.x >> 6);
    const float e = E[(size_t)n * DDIM + lane];
    float ss = e * e;
#pragma unroll
    for (int o = 32; o > 0; o >>= 1) ss += __shfl_xor(ss, o);
    if (lane == 0) normInv[n] = rsqrtf(ss);
}

// ===== k_accum: block = 16-row n-tile x all 2048 b.
// Stage: burst-gather G tile from R (global, rloc-major -> per-row L2 reuse,
//        ~2 MB concurrent row footprint per XCD << 4 MB L2), u8-encode -> LDS.
// Phase B: 2x mfma_f32_16x16x32_bf16 per b-tile, epilogue from LDS,
//          avg from rowsum/rowcnt, per-block partials (no atomics). =====
__global__ __launch_bounds__(256) void k_accum(
    const float* __restrict__ R, const float* __restrict__ E,
    const int* __restrict__ iidx, const u16* __restrict__ Ubf,
    const int2* __restrict__ qinfo,
    const float* __restrict__ rowsum, const float* __restrict__ rowcnt,
    const float* __restrict__ normInv, float2* __restrict__ partials)
{
    __shared__ u8 g[16][GSTR8];       // 32.9 KB

    const int tid  = threadIdx.x;
    const int lane = tid & 63;
    const int wid  = tid >> 6;
    const int lo   = lane & 15;
    const int hi   = lane >> 4;
    const int n0   = blockIdx.x * 16;

    // hoist this thread's 8 item indices (reused for all 16 rows)
    const int4 ii0 = ((const int4*)iidx)[tid];
    const int4 ii1 = ((const int4*)iidx)[tid + 256];

    // ---- Stage: 8 independent dword gathers per thread per row ----
#pragma unroll 2
    for (int rloc = 0; rloc < 16; ++rloc) {
        const float* Rn = R + (size_t)(n0 + rloc) * NI;
        const float a0 = Rn[ii0.x], a1 = Rn[ii0.y], a2 = Rn[ii0.z], a3 = Rn[ii0.w];
        const float b0 = Rn[ii1.x], b1 = Rn[ii1.y], b2 = Rn[ii1.z], b3 = Rn[ii1.w];
        uchar4 qa, qb;
        qa.x = enc_r(a0); qa.y = enc_r(a1); qa.z = enc_r(a2); qa.w = enc_r(a3);
        qb.x = enc_r(b0); qb.y = enc_r(b1); qb.z = enc_r(b2); qb.w = enc_r(b3);
        *(uchar4*)&g[rloc][tid * 4]         = qa;   // words tid       -> conflict-free
        *(uchar4*)&g[rloc][(tid + 256) * 4] = qb;   // words tid+256   -> conflict-free
    }

    // per-row avg and inv-norm for my 4 hi-rows
    float avr[4], ivr[4];
#pragma unroll
    for (int r = 0; r < 4; ++r) {
        const int nr = n0 + hi * 4 + r;
        const float cn = rowcnt[nr];
        avr[r] = (cn > 0.f) ? (rowsum[nr] / cn) : 0.f;
        ivr[r] = normInv[nr];
    }

    // A fragments (E rows n0..n0+15, K=64), bf16 on the fly
    short8 a[2];
#pragma unroll
    for (int kg = 0; kg < 2; ++kg) {
        const float* ep = E + (size_t)(n0 + lo) * DDIM + kg * 32 + hi * 8;
        const float4 e0 = *(const float4*)(ep);
        const float4 e1 = *(const float4*)(ep + 4);
        union { short8 v; u16 u[8]; } t;
        t.u[0] = f2bf(e0.x); t.u[1] = f2bf(e0.y); t.u[2] = f2bf(e0.z); t.u[3] = f2bf(e0.w);
        t.u[4] = f2bf(e1.x); t.u[5] = f2bf(e1.y); t.u[6] = f2bf(e1.z); t.u[7] = f2bf(e1.w);
        a[kg] = t.v;
    }

    __syncthreads();   // g tile complete

    float2* pout = partials + (size_t)blockIdx.x * BB;

#pragma unroll 1
    for (int j = 0; j < 32; ++j) {
        const int b0 = (j * 4 + wid) * 16;
        const int2 q = qinfo[b0 + lo];
        const float inv_mu = __int_as_float(q.y);

        const short8 bf0 = *(const short8*)(Ubf + (size_t)(b0 + lo) * DDIM + hi * 8);
        const short8 bf1 = *(const short8*)(Ubf + (size_t)(b0 + lo) * DDIM + 32 + hi * 8);

        f32x4 c = {0.f, 0.f, 0.f, 0.f};
        c = __builtin_amdgcn_mfma_f32_16x16x32_bf16(a[0], bf0, c, 0, 0, 0);
        c = __builtin_amdgcn_mfma_f32_16x16x32_bf16(a[1], bf1, c, 0, 0, 0);

        float fnum = 0.f, fden = 0.f;
#pragma unroll
        for (int r = 0; r < 4; ++r) {
            const int nr = n0 + hi * 4 + r;                 // C/D row (m89 mapping)
            const u8 qg = g[hi * 4 + r][b0 + lo];
            const bool valid = (qg != 0) && (nr != q.x);
            const float gv = (float)(int)qg * 0.02f + 0.98f;
            const float s  = valid ? c[r] * (inv_mu * ivr[r]) : 0.f;
            fnum += (gv - avr[r]) * s;                      // s==0 kills invalid
            fden += fabsf(s);
        }
        fnum += __shfl_xor(fnum, 16); fden += __shfl_xor(fden, 16);
        fnum += __shfl_xor(fnum, 32); fden += __shfl_xor(fden, 32);
        if (lane < 16) pout[b0 + lane] = make_float2(fnum, fden);
    }
}

// ===== k_final: reduce partials over 1024 n-tile blocks, finalize =====
__global__ __launch_bounds__(256) void k_final(
    const float2* __restrict__ partials, const int2* __restrict__ qinfo,
    const float* __restrict__ rowsum, const float* __restrict__ rowcnt,
    float* __restrict__ out)
{
    __shared__ float sn[8][32], sd[8][32];
    const int tid = threadIdx.x;
    const int bl  = tid & 31;
    const int ch  = tid >> 5;
    const int b   = blockIdx.x * 32 + bl;
    float n = 0.f, d = 0.f;
    for (int blk = ch; blk < NU / 16; blk += 8) {
        const float2 p = partials[(size_t)blk * BB + b];
        n += p.x; d += p.y;
    }
    sn[ch][bl] = n; sd[ch][bl] = d;
    __syncthreads();
    if (tid < 32) {
        float N = 0.f, D = 0.f;
#pragma unroll
        for (int c2 = 0; c2 < 8; ++c2) { N += sn[c2][tid]; D += sd[c2][tid]; }
        const int bb = blockIdx.x * 32 + tid;
        const int ub = qinfo[bb].x;
        const float cn = rowcnt[ub];
        const float au = (cn > 0.f) ? (rowsum[ub] / cn) : 0.f;
        out[bb] = (D == 0.f) ? au : (au + N / D);
    }
}

// ===== Launch =====
extern "C" void kernel_launch(void* const* d_in, const int* in_sizes, int n_in,
                              void* d_out, int out_size, void* d_ws, size_t ws_size,
                              hipStream_t stream)
{
    const float* R    = (const float*)d_in[0];
    const float* E    = (const float*)d_in[1];
    const int*   uidx = (const int*)d_in[2];
    const int*   iidx = (const int*)d_in[3];
    float* out = (float*)d_out;

    // ws carve: partials 16MiB | Ubf 256KB | qinfo 16KB | rowsum 64KB | rowcnt 64KB | normInv 64KB
    char* p = (char*)d_ws;
    float2* parts   = (float2*)p;  p += (size_t)(NU / 16) * BB * 8;
    u16*    Ubf     = (u16*)p;     p += (size_t)BB * DDIM * 2;
    int2*   qinfo   = (int2*)p;    p += (size_t)BB * 8;
    float*  rowsum  = (float*)p;   p += (size_t)NU * 4;
    float*  rowcnt  = (float*)p;   p += (size_t)NU * 4;
    float*  normInv = (float*)p;   p += (size_t)NU * 4;

    hipMemsetAsync(rowsum, 0, (size_t)NU * 2 * sizeof(float), stream);  // rowsum+rowcnt

    k_qprep<<<BB / 4, 256, 0, stream>>>(E, uidx, Ubf, qinfo);
    k_sums<<<NU, 256, 0, stream>>>(R, rowsum, rowcnt);
    k_enorm<<<NU / 4, 256, 0, stream>>>(E, normInv);
    k_accum<<<NU / 16, 256, 0, stream>>>(R, E, iidx, Ubf, qinfo, rowsum, rowcnt, normInv, parts);
    k_final<<<BB / 32, 256, 0, stream>>>(parts, qinfo, rowsum, rowcnt, out);
}